// Round 1
// baseline (513.103 us; speedup 1.0000x reference)
//
#include <hip/hip_runtime.h>

// Problem constants (SPADELight): x[8,128,256,256] f32, segmap[8,20,256,256] f32,
// weight[20,128] f32, bias[20,128] f32 -> out[8,128,256,256] f32.
constexpr int N_ = 8;
constexpr int C_ = 128;
constexpr int H_ = 256;
constexpr int W_ = 256;
constexpr int L_ = 20;
constexpr int HW = H_ * W_;           // 65536
constexpr float EPS = 1e-5f;

// ---------------------------------------------------------------------------
// Kernel 1: per-(n,c) mean and inv-std over HW. One block per (n,c).
// ---------------------------------------------------------------------------
__global__ __launch_bounds__(256) void spade_stats(const float* __restrict__ x,
                                                   float* __restrict__ stats) {
    const int nc = blockIdx.x;                       // 0..1023
    const float4* xp = reinterpret_cast<const float4*>(x + (size_t)nc * HW);

    float s = 0.f, s2 = 0.f;
    #pragma unroll 4
    for (int i = threadIdx.x; i < HW / 4; i += 256) {   // 64 iters/thread
        float4 v = xp[i];
        s  += v.x + v.y + v.z + v.w;
        s2 += v.x * v.x + v.y * v.y + v.z * v.z + v.w * v.w;
    }

    // wave64 butterfly reduce
    #pragma unroll
    for (int off = 32; off > 0; off >>= 1) {
        s  += __shfl_down(s, off, 64);
        s2 += __shfl_down(s2, off, 64);
    }

    __shared__ float ls[4], ls2[4];
    const int wid = threadIdx.x >> 6;
    const int lane = threadIdx.x & 63;
    if (lane == 0) { ls[wid] = s; ls2[wid] = s2; }
    __syncthreads();
    if (threadIdx.x == 0) {
        float ts  = ls[0] + ls[1] + ls[2] + ls[3];
        float ts2 = ls2[0] + ls2[1] + ls2[2] + ls2[3];
        float mean = ts / (float)HW;
        float var  = ts2 / (float)HW - mean * mean;   // biased var, matches ref
        stats[2 * nc]     = mean;
        stats[2 * nc + 1] = rsqrtf(var + EPS);
    }
}

// ---------------------------------------------------------------------------
// Kernel 2: per-pixel argmax over L=20 segmap channels -> uchar class id.
// Each thread owns 4 consecutive pixels (float4 per class, coalesced).
// ---------------------------------------------------------------------------
__global__ __launch_bounds__(256) void spade_argmax(const float* __restrict__ seg,
                                                    unsigned char* __restrict__ cls) {
    const int t = blockIdx.x * 256 + threadIdx.x;    // 4 pixels per thread
    const int per_n = HW / 4;                        // 16384 (multiple of 256)
    const int n  = t / per_n;
    const int p4 = (t - n * per_n) * 4;

    const float* base = seg + (size_t)n * L_ * HW + p4;
    float4 best = *reinterpret_cast<const float4*>(base);
    uchar4 bi = {0, 0, 0, 0};
    #pragma unroll
    for (int l = 1; l < L_; ++l) {
        float4 v = *reinterpret_cast<const float4*>(base + (size_t)l * HW);
        if (v.x > best.x) { best.x = v.x; bi.x = (unsigned char)l; }  // strict > :
        if (v.y > best.y) { best.y = v.y; bi.y = (unsigned char)l; }  // first-max
        if (v.z > best.z) { best.z = v.z; bi.z = (unsigned char)l; }  // tie rule
        if (v.w > best.w) { best.w = v.w; bi.w = (unsigned char)l; }
    }
    *reinterpret_cast<uchar4*>(cls + (size_t)n * HW + p4) = bi;
}

// ---------------------------------------------------------------------------
// Kernel 3: out = (x - mean) * invstd * weight[cls][c] + bias[cls][c]
//         = fmaf(x, scale[cls], shift[cls])  with per-block (n,c) params.
// 8 blocks per (n,c), each covers 8192 pixels (256 thr x 8 float4).
// ---------------------------------------------------------------------------
__global__ __launch_bounds__(256) void spade_apply(const float* __restrict__ x,
                                                   const float* __restrict__ weight,
                                                   const float* __restrict__ bias,
                                                   const float* __restrict__ stats,
                                                   const unsigned char* __restrict__ cls,
                                                   float* __restrict__ out) {
    const int bid   = blockIdx.x;
    const int nc    = bid >> 3;      // 8 chunks per (n,c)
    const int chunk = bid & 7;
    const int n = nc >> 7;           // C_=128
    const int c = nc & (C_ - 1);

    const float mean = stats[2 * nc];
    const float inv  = stats[2 * nc + 1];

    __shared__ float s_scale[L_], s_shift[L_];
    if (threadIdx.x < L_) {
        const int l = threadIdx.x;
        float wv = weight[l * C_ + c];
        float bv = bias[l * C_ + c];
        float sc = inv * wv;
        s_scale[l] = sc;
        s_shift[l] = bv - mean * sc;   // (x-mean)*inv*w + b == x*sc + (b - mean*sc)
    }
    __syncthreads();

    const size_t base = (size_t)nc * HW + (size_t)chunk * 8192;
    const float4* xp = reinterpret_cast<const float4*>(x + base);
    float4*       op = reinterpret_cast<float4*>(out + base);
    const uchar4* cp = reinterpret_cast<const uchar4*>(cls + (size_t)n * HW + chunk * 8192);

    #pragma unroll
    for (int i = 0; i < 8; ++i) {
        const int idx = i * 256 + threadIdx.x;
        float4 v  = xp[idx];
        uchar4 cc = cp[idx];
        float4 r;
        r.x = fmaf(v.x, s_scale[cc.x], s_shift[cc.x]);
        r.y = fmaf(v.y, s_scale[cc.y], s_shift[cc.y]);
        r.z = fmaf(v.z, s_scale[cc.z], s_shift[cc.z]);
        r.w = fmaf(v.w, s_scale[cc.w], s_shift[cc.w]);
        op[idx] = r;
    }
}

// ---------------------------------------------------------------------------
extern "C" void kernel_launch(void* const* d_in, const int* in_sizes, int n_in,
                              void* d_out, int out_size, void* d_ws, size_t ws_size,
                              hipStream_t stream) {
    const float* x      = (const float*)d_in[0];
    const float* segmap = (const float*)d_in[1];
    const float* weight = (const float*)d_in[2];
    const float* bias   = (const float*)d_in[3];
    float* out = (float*)d_out;

    // workspace layout: stats[1024*2] f32 (8 KB), then cls bytes (512 KB)
    float* stats = (float*)d_ws;
    unsigned char* cls = (unsigned char*)d_ws + 8192;

    spade_stats<<<N_ * C_, 256, 0, stream>>>(x, stats);
    spade_argmax<<<(N_ * HW / 4) / 256, 256, 0, stream>>>(segmap, cls);
    spade_apply<<<N_ * C_ * 8, 256, 0, stream>>>(x, weight, bias, stats, cls, out);
}